// Round 1
// baseline (364.167 us; speedup 1.0000x reference)
//
#include <hip/hip_runtime.h>

#define B_ROWS 16384
#define C_DIM  2048
#define BLK    256
#define CHUNK  8                      // C_DIM / BLK floats per thread per modality
#define RPB    32                     // rows per block  (B_ROWS / gridDim)
#define GROUP  8                      // rows between cross-wave barriers

// v += dpp_move(v); old = 0 so out-of-range/masked lanes contribute identity.
#define DPP_ADD(v, ctrl, rmask) \
  v += __int_as_float(__builtin_amdgcn_update_dpp(0, __float_as_int(v), (ctrl), (rmask), 0xf, false))

// Classic GCN/CDNA full-wave64 sum on the VALU pipe (no LDS/ds_swizzle).
// Result valid in lane 63.
__device__ __forceinline__ float wave_sum64(float v) {
  DPP_ADD(v, 0x111, 0xf);  // row_shr:1
  DPP_ADD(v, 0x112, 0xf);  // row_shr:2
  DPP_ADD(v, 0x114, 0xf);  // row_shr:4
  DPP_ADD(v, 0x118, 0xf);  // row_shr:8   -> lane15 of each row16 has row sum
  DPP_ADD(v, 0x142, 0xa);  // row_bcast:15 -> rows 1,3
  DPP_ADD(v, 0x143, 0xc);  // row_bcast:31 -> rows 2,3; lane 63 = full sum
  return v;
}

__global__ __launch_bounds__(BLK, 2)
void maff_fused(const float* __restrict__ s_f,
                const float* __restrict__ g_f,
                const float* __restrict__ v_f,
                const float* __restrict__ W_aff,
                const float* __restrict__ b_aff,
                const float* __restrict__ W_cls,
                const float* __restrict__ b_cls,
                float* __restrict__ out)
{
  const int t    = threadIdx.x;
  const int lane = t & 63;
  const int wave = t >> 6;
  const int c0   = t * CHUNK;

  // ---- per-thread weight slice, kept in VGPRs across all 32 rows ----
  // wa[m][i][j]: W_aff[(m*C + c0+i), j]   wc[m][i][k]: W_cls[(m*C + c0+i), k]
  float wa[3][CHUNK][3];
  float wc[3][CHUNK][2];
#pragma unroll
  for (int m = 0; m < 3; ++m) {
#pragma unroll
    for (int i = 0; i < CHUNK; ++i) {
      const int cc = m * C_DIM + c0 + i;
      wa[m][i][0] = W_aff[cc * 3 + 0];
      wa[m][i][1] = W_aff[cc * 3 + 1];
      wa[m][i][2] = W_aff[cc * 3 + 2];
      wc[m][i][0] = W_cls[cc * 2 + 0];
      wc[m][i][1] = W_cls[cc * 2 + 1];
    }
  }
  const float ba0 = b_aff[0], ba1 = b_aff[1], ba2 = b_aff[2];
  const float bc0 = b_cls[0], bc1 = b_cls[1];

  // double-buffered per-group reduction scratch: [buf][row-in-group][wave][9]
  __shared__ float red[2][GROUP][4][9];

  const int row0 = blockIdx.x * RPB;

  // ---- preload row 0 (6 x float4 per thread) ----
  float4 cs0, cs1, cg0, cg1, cv0, cv1;
  {
    const size_t off = (size_t)row0 * C_DIM + c0;
    cs0 = *(const float4*)(s_f + off); cs1 = *(const float4*)(s_f + off + 4);
    cg0 = *(const float4*)(g_f + off); cg1 = *(const float4*)(g_f + off + 4);
    cv0 = *(const float4*)(v_f + off); cv1 = *(const float4*)(v_f + off + 4);
  }

  for (int r = 0; r < RPB; ++r) {
    // ---- prefetch next row (clamped; last iter harmlessly reloads row0) ----
    const int    pr   = (r + 1 < RPB) ? (row0 + r + 1) : row0;
    const size_t poff = (size_t)pr * C_DIM + c0;
    float4 ns0 = *(const float4*)(s_f + poff);
    float4 ns1 = *(const float4*)(s_f + poff + 4);
    float4 ng0 = *(const float4*)(g_f + poff);
    float4 ng1 = *(const float4*)(g_f + poff + 4);
    float4 nv0 = *(const float4*)(v_f + poff);
    float4 nv1 = *(const float4*)(v_f + poff + 4);

    float fs[CHUNK], fg[CHUNK], fv[CHUNK];
    fs[0]=cs0.x; fs[1]=cs0.y; fs[2]=cs0.z; fs[3]=cs0.w;
    fs[4]=cs1.x; fs[5]=cs1.y; fs[6]=cs1.z; fs[7]=cs1.w;
    fg[0]=cg0.x; fg[1]=cg0.y; fg[2]=cg0.z; fg[3]=cg0.w;
    fg[4]=cg1.x; fg[5]=cg1.y; fg[6]=cg1.z; fg[7]=cg1.w;
    fv[0]=cv0.x; fv[1]=cv0.y; fv[2]=cv0.z; fv[3]=cv0.w;
    fv[4]=cv1.x; fv[5]=cv1.y; fv[6]=cv1.z; fv[7]=cv1.w;

    // ---- 15 FMAs per c; aff columns merged across modalities (9 accums) ----
    float a0=0.f, a1=0.f, a2=0.f;
    float d00=0.f, d01=0.f, d10=0.f, d11=0.f, d20=0.f, d21=0.f;
#pragma unroll
    for (int i = 0; i < CHUNK; ++i) {
      a0 = fmaf(fs[i], wa[0][i][0], a0);
      a1 = fmaf(fs[i], wa[0][i][1], a1);
      a2 = fmaf(fs[i], wa[0][i][2], a2);
      a0 = fmaf(fg[i], wa[1][i][0], a0);
      a1 = fmaf(fg[i], wa[1][i][1], a1);
      a2 = fmaf(fg[i], wa[1][i][2], a2);
      a0 = fmaf(fv[i], wa[2][i][0], a0);
      a1 = fmaf(fv[i], wa[2][i][1], a1);
      a2 = fmaf(fv[i], wa[2][i][2], a2);
      d00 = fmaf(fs[i], wc[0][i][0], d00);
      d01 = fmaf(fs[i], wc[0][i][1], d01);
      d10 = fmaf(fg[i], wc[1][i][0], d10);
      d11 = fmaf(fg[i], wc[1][i][1], d11);
      d20 = fmaf(fv[i], wc[2][i][0], d20);
      d21 = fmaf(fv[i], wc[2][i][1], d21);
    }

    // ---- wave-level reduction on VALU pipe (DPP) ----
    a0  = wave_sum64(a0);  a1  = wave_sum64(a1);  a2  = wave_sum64(a2);
    d00 = wave_sum64(d00); d01 = wave_sum64(d01);
    d10 = wave_sum64(d10); d11 = wave_sum64(d11);
    d20 = wave_sum64(d20); d21 = wave_sum64(d21);

    const int gslot = r & (GROUP - 1);
    const int gbuf  = (r / GROUP) & 1;
    if (lane == 63) {
      float* dst = &red[gbuf][gslot][wave][0];
      dst[0] = a0;  dst[1] = a1;  dst[2] = a2;
      dst[3] = d00; dst[4] = d01; dst[5] = d10;
      dst[6] = d11; dst[7] = d20; dst[8] = d21;
    }

    // ---- every GROUP rows: one barrier, then 8 threads finish 8 rows ----
    if (gslot == GROUP - 1) {
      __syncthreads();
      if (t < GROUP) {
        const float* q = &red[gbuf][t][0][0];   // 4 waves x 9 floats
        float A0  = q[0] + q[ 9] + q[18] + q[27] + ba0;
        float A1  = q[1] + q[10] + q[19] + q[28] + ba1;
        float A2  = q[2] + q[11] + q[20] + q[29] + ba2;
        float D00 = q[3] + q[12] + q[21] + q[30];
        float D01 = q[4] + q[13] + q[22] + q[31];
        float D10 = q[5] + q[14] + q[23] + q[32];
        float D11 = q[6] + q[15] + q[24] + q[33];
        float D20 = q[7] + q[16] + q[25] + q[34];
        float D21 = q[8] + q[17] + q[26] + q[35];

        // softmax over the 3 attention logits
        float mx = fmaxf(A0, fmaxf(A1, A2));
        float e0 = __expf(A0 - mx), e1 = __expf(A1 - mx), e2 = __expf(A2 - mx);
        float inv = 1.0f / (e0 + e1 + e2);
        float t0 = e0 * inv, t1 = e1 * inv, t2 = e2 * inv;

        // classifier logits + 2-way softmax
        float L0 = t0 * D00 + t1 * D10 + t2 * D20 + bc0;
        float L1 = t0 * D01 + t1 * D11 + t2 * D21 + bc1;
        float mm = fmaxf(L0, L1);
        float x0 = __expf(L0 - mm), x1 = __expf(L1 - mm);
        float is = 1.0f / (x0 + x1);

        const int row = row0 + (r - (GROUP - 1)) + t;
        *(float2*)(out + (size_t)row * 2) = make_float2(x0 * is, x1 * is);
      }
      // no second barrier: double-buffered red[] — buf p is only rewritten
      // two groups later, after the next barrier has been passed.
    }

    cs0 = ns0; cs1 = ns1; cg0 = ng0; cg1 = ng1; cv0 = nv0; cv1 = nv1;
  }
}

extern "C" void kernel_launch(void* const* d_in, const int* in_sizes, int n_in,
                              void* d_out, int out_size, void* d_ws, size_t ws_size,
                              hipStream_t stream) {
  const float* s_f   = (const float*)d_in[0];
  const float* g_f   = (const float*)d_in[1];
  const float* v_f   = (const float*)d_in[2];
  const float* W_aff = (const float*)d_in[3];
  const float* b_aff = (const float*)d_in[4];
  const float* W_cls = (const float*)d_in[5];
  const float* b_cls = (const float*)d_in[6];
  float* out = (float*)d_out;

  dim3 grid(B_ROWS / RPB);   // 512 blocks x 32 rows
  dim3 block(BLK);
  maff_fused<<<grid, block, 0, stream>>>(s_f, g_f, v_f, W_aff, b_aff, W_cls, b_cls, out);
}